// Round 6
// baseline (512.775 us; speedup 1.0000x reference)
//
#include <hip/hip_runtime.h>
#include <hip/hip_bf16.h>

typedef unsigned short u16;
typedef unsigned int u32;
typedef __attribute__((ext_vector_type(8))) short short8;
typedef __attribute__((ext_vector_type(2))) unsigned int u32x2;
typedef __attribute__((ext_vector_type(4))) float f32x4;

__device__ __forceinline__ u16 f2bf(float x) {
  __hip_bfloat16 h = __float2bfloat16(x);
  return *reinterpret_cast<u16*>(&h);
}
__device__ __forceinline__ u32 pk2(float a, float b) {
  return (u32)f2bf(a) | ((u32)f2bf(b) << 16);
}
__device__ __forceinline__ float bflo(u32 u) { return __uint_as_float(u << 16); }
__device__ __forceinline__ float bfhi(u32 u) { return __uint_as_float(u & 0xffff0000u); }

// ---------------- weight transposes (48 blocks) + bias fragment precompute (block 48) ----------------
__global__ __launch_bounds__(256) void k_wprep4(const float* __restrict__ qkv_w,
                                                const float* __restrict__ proj_w,
                                                const float* __restrict__ w1,
                                                const float* __restrict__ w2,
                                                const float* __restrict__ btab,
                                                u16* __restrict__ qkvT, u16* __restrict__ projT,
                                                u16* __restrict__ w1T, u16* __restrict__ w2T,
                                                u32* __restrict__ bfrag) {
  const int b = blockIdx.x, t = threadIdx.x;
  if (b == 48) {
    // bias fragments: for attn-thread t (h=t>>6, m=t&15, q4=(t>>4)&3), element e=(ti*4+tj)*4+rr
    const int h = t >> 6, m = t & 15, q4 = (t >> 4) & 3;
    const int my = m >> 2, mz = m & 3;
    for (int g = 0; g < 16; ++g) {
      int ti = g >> 2, tj = g & 3;
      int base = 11 * (tj - ti + 3) + (my - q4 + 3) + (mz + 3);
      float v0 = btab[(base - 0) * 4 + h];
      float v1 = btab[(base - 1) * 4 + h];
      float v2 = btab[(base - 2) * 4 + h];
      float v3 = btab[(base - 3) * 4 + h];
      bfrag[(g * 256 + t) * 2 + 0] = pk2(v0, v1);
      bfrag[(g * 256 + t) * 2 + 1] = pk2(v2, v3);
    }
    return;
  }
  __shared__ float tile[64][65];
  const float* src; u16* dst; int K, N, tk, tn;
  if (b < 12)      { src = qkv_w;  dst = qkvT;  K = 128; N = 384; tk = b / 6;        tn = b % 6; }
  else if (b < 16) { src = proj_w; dst = projT; K = 128; N = 128; tk = (b - 12) / 2; tn = (b - 12) % 2; }
  else if (b < 32) { src = w1;     dst = w1T;   K = 128; N = 512; tk = (b - 16) / 8; tn = (b - 16) % 8; }
  else             { src = w2;     dst = w2T;   K = 512; N = 128; tk = (b - 32) / 2; tn = (b - 32) % 2; }
  const int rb = t >> 6, c = t & 63;
  #pragma unroll
  for (int i = 0; i < 16; ++i) {
    int r = i * 4 + rb;
    tile[r][c] = src[(size_t)(tk * 64 + r) * N + tn * 64 + c];
  }
  __syncthreads();
  #pragma unroll
  for (int i = 0; i < 16; ++i) {
    int rr = i * 4 + rb;
    dst[(size_t)(tn * 64 + rr) * K + tk * 64 + c] = f2bf(tile[c][rr]);
  }
}

// ---------------- R6: one kernel per window, 53248 B LDS -> 3 blocks/CU ----------------
// Regions (bytes):
//   [0,17408)      A (LN1, stride 136) -> [b1.5] Q (stride 136) -> [b2] P0@0,P1@8704 -> [b3] O [64][136]
//   [17408,34816)  K (stride 136)      -> [b2] P2@17408,P3@26112 -> [b4] A2 [64][136]
//   [34816,53248)  Vt [4][32][72]      -> [b5] H0@34816,H1@44032 [64][72];  red[64][8]f32 @34816 (pre-b5)
// P stride = 68 u16 (136 B/row): b64-aligned rows, conflict-free (34 dw = 2 mod 32).
// All GEMMs oriented so acc r-quads are destination-contiguous (b64/b128 packed writes).
// X (residual) lives in registers from proj to epilogue (proj and MLP-GEMM2 share geometry).
__global__ __launch_bounds__(256, 3) void k_all(const float* __restrict__ inputs,
                                                const u16* __restrict__ qkvT,
                                                const u16* __restrict__ projT,
                                                const float* __restrict__ proj_b,
                                                const u32* __restrict__ bfrag,
                                                const float* __restrict__ g1,
                                                const float* __restrict__ b1,
                                                const u16* __restrict__ w1T,
                                                const u16* __restrict__ w2T,
                                                const float* __restrict__ g2,
                                                const float* __restrict__ b2,
                                                const float* __restrict__ bb1,
                                                const float* __restrict__ bb2,
                                                float* __restrict__ out) {
  __shared__ __align__(16) char lds[53248];

  const int t = threadIdx.x, wv = t >> 6, lane = t & 63;
  const int m = lane & 15, q4 = lane >> 4;
  const int bw = blockIdx.x;
  const int wbox = bw & 511, bsm = bw >> 9;
  const int gx = wbox >> 6, gy = (wbox >> 3) & 7, gz = wbox & 7;

  // ---- LN1 with roll/partition gather (row r1), seg-reduce via shfl ----
  {
    const int r1 = t >> 2, seg = t & 3;
    const int ix = r1 >> 4, iy = (r1 >> 2) & 3, iz = r1 & 3;
    const int X = (gx * 4 + ix + 2) & 31, Y = (gy * 4 + iy + 2) & 31, Z = (gz * 4 + iz + 2) & 31;
    const size_t orig = ((size_t)bsm << 15) + (size_t)(X * 1024 + Y * 32 + Z);
    const float4* x4 = (const float4*)(inputs + orig * 128 + seg * 32);
    float vals[32];
    float s = 0.f, ss = 0.f;
    #pragma unroll
    for (int i = 0; i < 8; ++i) {
      float4 v = x4[i];
      vals[4 * i] = v.x; vals[4 * i + 1] = v.y; vals[4 * i + 2] = v.z; vals[4 * i + 3] = v.w;
      s += v.x + v.y + v.z + v.w;
      ss += v.x * v.x + v.y * v.y + v.z * v.z + v.w * v.w;
    }
    s += __shfl_xor(s, 1, 64);  s += __shfl_xor(s, 2, 64);
    ss += __shfl_xor(ss, 1, 64); ss += __shfl_xor(ss, 2, 64);
    float mean = s * 0.0078125f;
    float var = ss * 0.0078125f - mean * mean;
    float rs = rsqrtf(var + 1e-5f);
    #pragma unroll
    for (int v8 = 0; v8 < 4; ++v8) {
      short8 w;
      #pragma unroll
      for (int j = 0; j < 8; ++j) {
        int c = seg * 32 + v8 * 8 + j;
        w[j] = (short)f2bf((vals[v8 * 8 + j] - mean) * rs * g1[c] + b1[c]);
      }
      *(short8*)(lds + r1 * 272 + seg * 64 + v8 * 16) = w;
    }
  }
  __syncthreads();   // (b1) A ready

  // ---- A fragments (all 64 rows) ----
  short8 af[4][4];   // [kc][jt] rows jt*16+m, cols kc*32+q4*8
  #pragma unroll
  for (int kc = 0; kc < 4; ++kc)
    #pragma unroll
    for (int jt = 0; jt < 4; ++jt)
      af[kc][jt] = *(const short8*)(lds + (jt * 16 + m) * 272 + kc * 64 + q4 * 16);
  __syncthreads();   // (b1.5) all af reads done -> Q may overlay A

  f32x4 zero = {0.f, 0.f, 0.f, 0.f};

  // ---- Q GEMM (swapped: D[col][tok]) -> Q[tok][col] b64 writes, scaled ----
  {
    short8 wq[4][2];
    #pragma unroll
    for (int kc = 0; kc < 4; ++kc)
      #pragma unroll
      for (int it = 0; it < 2; ++it)
        wq[kc][it] = *(const short8*)(qkvT + (size_t)(wv * 32 + it * 16 + m) * 128 + kc * 32 + q4 * 8);
    f32x4 acc[2][4];
    #pragma unroll
    for (int it = 0; it < 2; ++it)
      #pragma unroll
      for (int jt = 0; jt < 4; ++jt) acc[it][jt] = zero;
    #pragma unroll
    for (int kc = 0; kc < 4; ++kc)
      #pragma unroll
      for (int it = 0; it < 2; ++it)
        #pragma unroll
        for (int jt = 0; jt < 4; ++jt)
          acc[it][jt] = __builtin_amdgcn_mfma_f32_16x16x32_bf16(wq[kc][it], af[kc][jt], acc[it][jt], 0, 0, 0);
    #pragma unroll
    for (int it = 0; it < 2; ++it)
      #pragma unroll
      for (int jt = 0; jt < 4; ++jt) {
        f32x4 a = acc[it][jt];
        u32x2 w = {pk2(a[0] * 0.17677669529663687f, a[1] * 0.17677669529663687f),
                   pk2(a[2] * 0.17677669529663687f, a[3] * 0.17677669529663687f)};
        *(u32x2*)(lds + (jt * 16 + m) * 272 + (wv * 32 + it * 16 + q4 * 4) * 2) = w;
      }
  }

  // ---- K GEMM (swapped) -> K[tok][col] @17408 ----
  {
    short8 wk[4][2];
    #pragma unroll
    for (int kc = 0; kc < 4; ++kc)
      #pragma unroll
      for (int it = 0; it < 2; ++it)
        wk[kc][it] = *(const short8*)(qkvT + (size_t)(128 + wv * 32 + it * 16 + m) * 128 + kc * 32 + q4 * 8);
    f32x4 acc[2][4];
    #pragma unroll
    for (int it = 0; it < 2; ++it)
      #pragma unroll
      for (int jt = 0; jt < 4; ++jt) acc[it][jt] = zero;
    #pragma unroll
    for (int kc = 0; kc < 4; ++kc)
      #pragma unroll
      for (int it = 0; it < 2; ++it)
        #pragma unroll
        for (int jt = 0; jt < 4; ++jt)
          acc[it][jt] = __builtin_amdgcn_mfma_f32_16x16x32_bf16(wk[kc][it], af[kc][jt], acc[it][jt], 0, 0, 0);
    #pragma unroll
    for (int it = 0; it < 2; ++it)
      #pragma unroll
      for (int jt = 0; jt < 4; ++jt) {
        f32x4 a = acc[it][jt];
        u32x2 w = {pk2(a[0], a[1]), pk2(a[2], a[3])};
        *(u32x2*)(lds + 17408 + (jt * 16 + m) * 272 + (wv * 32 + it * 16 + q4 * 4) * 2) = w;
      }
  }

  // ---- V GEMM (original: D[tok][d]) -> Vt[d][tok] @34816, b64 (tok-quads contiguous) ----
  {
    short8 wvv[4][2];
    #pragma unroll
    for (int kc = 0; kc < 4; ++kc)
      #pragma unroll
      for (int n2 = 0; n2 < 2; ++n2)
        wvv[kc][n2] = *(const short8*)(qkvT + (size_t)(256 + wv * 32 + n2 * 16 + m) * 128 + kc * 32 + q4 * 8);
    f32x4 acc[4][2];
    #pragma unroll
    for (int mt = 0; mt < 4; ++mt)
      #pragma unroll
      for (int n2 = 0; n2 < 2; ++n2) acc[mt][n2] = zero;
    #pragma unroll
    for (int kc = 0; kc < 4; ++kc)
      #pragma unroll
      for (int mt = 0; mt < 4; ++mt)
        #pragma unroll
        for (int n2 = 0; n2 < 2; ++n2)
          acc[mt][n2] = __builtin_amdgcn_mfma_f32_16x16x32_bf16(af[kc][mt], wvv[kc][n2], acc[mt][n2], 0, 0, 0);
    #pragma unroll
    for (int mt = 0; mt < 4; ++mt)
      #pragma unroll
      for (int n2 = 0; n2 < 2; ++n2) {
        f32x4 a = acc[mt][n2];
        u32x2 w = {pk2(a[0], a[1]), pk2(a[2], a[3])};
        *(u32x2*)(lds + 34816 + wv * 4608 + (n2 * 16 + m) * 144 + mt * 32 + q4 * 8) = w;
      }
  }

  // ---- qf/kf fragments (own head band; same-wave data) ----
  short8 qf[4], kf[4];
  #pragma unroll
  for (int ti = 0; ti < 4; ++ti) {
    qf[ti] = *(const short8*)(lds + (ti * 16 + m) * 272 + wv * 64 + q4 * 16);
    kf[ti] = *(const short8*)(lds + 17408 + (ti * 16 + m) * 272 + wv * 64 + q4 * 16);
  }
  // bias fragments from global (L2-hot)
  u32x2 bu[16];
  #pragma unroll
  for (int g = 0; g < 16; ++g)
    bu[g] = *(const u32x2*)(bfrag + (g * 256 + t) * 2);
  __syncthreads();   // (b2) all Q/K reads done -> P may overlay Q+K

  // ---- S^T = mfma(K,Q): rows k = ti*16+q4*4+rr, cols q = tj*16+m ----
  f32x4 S[4][4];
  #pragma unroll
  for (int ti = 0; ti < 4; ++ti)
    #pragma unroll
    for (int tj = 0; tj < 4; ++tj) S[ti][tj] = zero;
  #pragma unroll
  for (int ti = 0; ti < 4; ++ti)
    #pragma unroll
    for (int tj = 0; tj < 4; ++tj)
      S[ti][tj] = __builtin_amdgcn_mfma_f32_16x16x32_bf16(kf[ti], qf[tj], S[ti][tj], 0, 0, 0);

  // ---- bias + mask ----
  int catx[4], caty[4], catz[4];
  #pragma unroll
  for (int a = 0; a < 4; ++a) {
    catx[a] = (gx < 7) ? 0 : ((a < 2) ? 1 : 2);
    caty[a] = (gy < 7) ? 0 : ((a < 2) ? 1 : 2);
    catz[a] = (gz < 7) ? 0 : ((a < 2) ? 1 : 2);
  }
  const int cy = (m >> 2) & 3, cz = m & 3;
  int labq[4], labk[16];
  #pragma unroll
  for (int tj = 0; tj < 4; ++tj) labq[tj] = catx[tj] * 9 + caty[cy] * 3 + catz[cz];
  #pragma unroll
  for (int ti = 0; ti < 4; ++ti)
    #pragma unroll
    for (int rr = 0; rr < 4; ++rr) labk[ti * 4 + rr] = catx[ti] * 9 + caty[q4] * 3 + catz[rr];

  #pragma unroll
  for (int ti = 0; ti < 4; ++ti)
    #pragma unroll
    for (int tj = 0; tj < 4; ++tj) {
      u32x2 bp = bu[ti * 4 + tj];
      #pragma unroll
      for (int rr = 0; rr < 4; ++rr) {
        float bv = (rr & 1) ? bfhi(bp[rr >> 1]) : bflo(bp[rr >> 1]);
        float v = S[ti][tj][rr] + bv;
        if (labk[ti * 4 + rr] != labq[tj]) v -= 100.f;
        S[ti][tj][rr] = v;
      }
    }

  // ---- softmax over k (in-reg 16 + shfl over q4-lanes) ----
  float mx[4], sm[4];
  #pragma unroll
  for (int tj = 0; tj < 4; ++tj) {
    float v = fmaxf(fmaxf(S[0][tj][0], S[0][tj][1]), fmaxf(S[0][tj][2], S[0][tj][3]));
    #pragma unroll
    for (int ti = 1; ti < 4; ++ti)
      v = fmaxf(v, fmaxf(fmaxf(S[ti][tj][0], S[ti][tj][1]), fmaxf(S[ti][tj][2], S[ti][tj][3])));
    v = fmaxf(v, __shfl_xor(v, 16, 64));
    v = fmaxf(v, __shfl_xor(v, 32, 64));
    mx[tj] = v;
  }
  #pragma unroll
  for (int tj = 0; tj < 4; ++tj) {
    float s = 0.f;
    #pragma unroll
    for (int ti = 0; ti < 4; ++ti)
      #pragma unroll
      for (int rr = 0; rr < 4; ++rr) {
        float e = __expf(S[ti][tj][rr] - mx[tj]);
        S[ti][tj][rr] = e;
        s += e;
      }
    s += __shfl_xor(s, 16, 64);
    s += __shfl_xor(s, 32, 64);
    sm[tj] = 1.f / s;
  }

  // ---- P[q][k] (stride 68 u16), per-head @ wv*8704; b64 writes (k-quads contiguous) ----
  #pragma unroll
  for (int ti = 0; ti < 4; ++ti)
    #pragma unroll
    for (int tj = 0; tj < 4; ++tj) {
      f32x4 a = S[ti][tj];
      u32x2 w = {pk2(a[0], a[1]), pk2(a[2], a[3])};
      *(u32x2*)(lds + wv * 8704 + (tj * 16 + m) * 136 + ti * 32 + q4 * 8) = w;
    }

  // ---- PV (swapped: D[d][q]) ----
  f32x4 accO[2][4];
  #pragma unroll
  for (int it = 0; it < 2; ++it)
    #pragma unroll
    for (int jt = 0; jt < 4; ++jt) accO[it][jt] = zero;
  #pragma unroll
  for (int ks = 0; ks < 2; ++ks) {
    short8 vb[2], pa[4];
    #pragma unroll
    for (int it = 0; it < 2; ++it)
      vb[it] = *(const short8*)(lds + 34816 + wv * 4608 + (it * 16 + m) * 144 + ks * 64 + q4 * 16);
    #pragma unroll
    for (int jt = 0; jt < 4; ++jt) {
      u32x2 lo = *(const u32x2*)(lds + wv * 8704 + (jt * 16 + m) * 136 + ks * 64 + q4 * 16);
      u32x2 hi = *(const u32x2*)(lds + wv * 8704 + (jt * 16 + m) * 136 + ks * 64 + q4 * 16 + 8);
      union { u32 u[4]; short8 s; } c;
      c.u[0] = lo[0]; c.u[1] = lo[1]; c.u[2] = hi[0]; c.u[3] = hi[1];
      pa[jt] = c.s;
    }
    #pragma unroll
    for (int it = 0; it < 2; ++it)
      #pragma unroll
      for (int jt = 0; jt < 4; ++jt)
        accO[it][jt] = __builtin_amdgcn_mfma_f32_16x16x32_bf16(vb[it], pa[jt], accO[it][jt], 0, 0, 0);
  }
  __syncthreads();   // (b3) all PV done -> P,Vt dead -> O may overlay P0/P1

  // ---- O[tok][d] @0 (stride 136), b64 writes, normalized ----
  #pragma unroll
  for (int it = 0; it < 2; ++it)
    #pragma unroll
    for (int jt = 0; jt < 4; ++jt) {
      f32x4 a = accO[it][jt];
      float sc = sm[jt];
      u32x2 w = {pk2(a[0] * sc, a[1] * sc), pk2(a[2] * sc, a[3] * sc)};
      *(u32x2*)(lds + (jt * 16 + m) * 272 + (wv * 32 + it * 16 + q4 * 4) * 2) = w;
    }
  __syncthreads();   // (b4) O ready

  // ---- proj (swapped: D[col][tok]); residual into registers ----
  int origjt[4];
  #pragma unroll
  for (int jt = 0; jt < 4; ++jt) {
    int X = (gx * 4 + jt + 2) & 31, Y = (gy * 4 + (m >> 2) + 2) & 31, Z = (gz * 4 + (m & 3) + 2) & 31;
    origjt[jt] = (bsm << 15) + X * 1024 + Y * 32 + Z;
  }
  f32x4 xr[2][4];
  {
    short8 bp[4][2], of[4][4];
    #pragma unroll
    for (int kc = 0; kc < 4; ++kc)
      #pragma unroll
      for (int it = 0; it < 2; ++it)
        bp[kc][it] = *(const short8*)(projT + (size_t)(wv * 32 + it * 16 + m) * 128 + kc * 32 + q4 * 8);
    f32x4 inr[2][4];
    #pragma unroll
    for (int it = 0; it < 2; ++it)
      #pragma unroll
      for (int jt = 0; jt < 4; ++jt)
        inr[it][jt] = *(const f32x4*)(inputs + (size_t)origjt[jt] * 128 + wv * 32 + it * 16 + q4 * 4);
    f32x4 pbv[2];
    #pragma unroll
    for (int it = 0; it < 2; ++it)
      pbv[it] = *(const f32x4*)(proj_b + wv * 32 + it * 16 + q4 * 4);
    #pragma unroll
    for (int kc = 0; kc < 4; ++kc)
      #pragma unroll
      for (int jt = 0; jt < 4; ++jt)
        of[kc][jt] = *(const short8*)(lds + (jt * 16 + m) * 272 + kc * 64 + q4 * 16);
    f32x4 acc[2][4];
    #pragma unroll
    for (int it = 0; it < 2; ++it)
      #pragma unroll
      for (int jt = 0; jt < 4; ++jt) acc[it][jt] = zero;
    #pragma unroll
    for (int kc = 0; kc < 4; ++kc)
      #pragma unroll
      for (int it = 0; it < 2; ++it)
        #pragma unroll
        for (int jt = 0; jt < 4; ++jt)
          acc[it][jt] = __builtin_amdgcn_mfma_f32_16x16x32_bf16(bp[kc][it], of[kc][jt], acc[it][jt], 0, 0, 0);
    #pragma unroll
    for (int it = 0; it < 2; ++it)
      #pragma unroll
      for (int jt = 0; jt < 4; ++jt)
        #pragma unroll
        for (int rr = 0; rr < 4; ++rr)
          xr[it][jt][rr] = 0.5f * (acc[it][jt][rr] + pbv[it][rr]) + inr[it][jt][rr];
  }
  __syncthreads();   // (b4.5) all O reads done -> A2/red regions writable

  // ---- LN2 stats (cross-wave via red @34816) ----
  float* red = (float*)(lds + 34816);   // [64 tok][8]: (wv -> s,ss pairs)
  {
    float sp[4], ssp[4];
    #pragma unroll
    for (int jt = 0; jt < 4; ++jt) {
      float s = 0.f, ss2 = 0.f;
      #pragma unroll
      for (int it = 0; it < 2; ++it)
        #pragma unroll
        for (int rr = 0; rr < 4; ++rr) {
          float v = xr[it][jt][rr];
          s += v; ss2 += v * v;
        }
      s += __shfl_xor(s, 16, 64);  s += __shfl_xor(s, 32, 64);
      ss2 += __shfl_xor(ss2, 16, 64); ss2 += __shfl_xor(ss2, 32, 64);
      sp[jt] = s; ssp[jt] = ss2;
    }
    if (q4 == 0) {
      #pragma unroll
      for (int jt = 0; jt < 4; ++jt) {
        red[(jt * 16 + m) * 8 + wv * 2 + 0] = sp[jt];
        red[(jt * 16 + m) * 8 + wv * 2 + 1] = ssp[jt];
      }
    }
  }
  __syncthreads();   // (b4.75) red ready

  // ---- normalize -> A2[tok][col] @17408 (b64 writes) ----
  {
    f32x4 g2v[2], b2v[2];
    #pragma unroll
    for (int it = 0; it < 2; ++it) {
      g2v[it] = *(const f32x4*)(g2 + wv * 32 + it * 16 + q4 * 4);
      b2v[it] = *(const f32x4*)(b2 + wv * 32 + it * 16 + q4 * 4);
    }
    #pragma unroll
    for (int jt = 0; jt < 4; ++jt) {
      f32x4 r0 = *(const f32x4*)(red + (jt * 16 + m) * 8);
      f32x4 r1 = *(const f32x4*)(red + (jt * 16 + m) * 8 + 4);
      float sum = r0[0] + r0[2] + r1[0] + r1[2];
      float sq  = r0[1] + r0[3] + r1[1] + r1[3];
      float mean = sum * 0.0078125f;
      float var = sq * 0.0078125f - mean * mean;
      float rs = rsqrtf(var + 1e-5f);
      #pragma unroll
      for (int it = 0; it < 2; ++it) {
        float n0 = (xr[it][jt][0] - mean) * rs * g2v[it][0] + b2v[it][0];
        float n1 = (xr[it][jt][1] - mean) * rs * g2v[it][1] + b2v[it][1];
        float n2 = (xr[it][jt][2] - mean) * rs * g2v[it][2] + b2v[it][2];
        float n3 = (xr[it][jt][3] - mean) * rs * g2v[it][3] + b2v[it][3];
        u32x2 w = {pk2(n0, n1), pk2(n2, n3)};
        *(u32x2*)(lds + 17408 + (jt * 16 + m) * 272 + (wv * 32 + it * 16 + q4 * 4) * 2) = w;
      }
    }
  }
  __syncthreads();   // (b5) A2 ready; red dead -> H0 writable

  // ---- MLP: GEMM1 swapped -> H[tok][hcol] b64; GEMM2 swapped -> acc[col][tok] ----
  short8 am[4][4];
  #pragma unroll
  for (int kc = 0; kc < 4; ++kc)
    #pragma unroll
    for (int jt = 0; jt < 4; ++jt)
      am[kc][jt] = *(const short8*)(lds + 17408 + (jt * 16 + m) * 272 + kc * 64 + q4 * 16);

  const u16* w1base = w1T + (size_t)(wv * 16 + m) * 128 + q4 * 8;
  short8 b1p0[4], b1p1[4];
  #pragma unroll
  for (int kc = 0; kc < 4; ++kc) b1p0[kc] = *(const short8*)(w1base + kc * 32);
  #pragma unroll
  for (int kc = 0; kc < 4; ++kc) b1p1[kc] = *(const short8*)(w1base + (size_t)64 * 128 + kc * 32);

  f32x4 acc[2][4];
  #pragma unroll
  for (int it = 0; it < 2; ++it)
    #pragma unroll
    for (int jt = 0; jt < 4; ++jt) acc[it][jt] = zero;

  #pragma unroll
  for (int nt = 0; nt < 8; ++nt) {
    char* Hb = lds + 34816 + (nt & 1) * 9216;
    // GEMM1 (swapped): D[hcol][tok]; hcol = nt*64 + wv*16 + q4*4 + rr
    f32x4 hacc[4];
    #pragma unroll
    for (int jt = 0; jt < 4; ++jt) hacc[jt] = zero;
    if (nt & 1) {
      #pragma unroll
      for (int kc = 0; kc < 4; ++kc)
        #pragma unroll
        for (int jt = 0; jt < 4; ++jt)
          hacc[jt] = __builtin_amdgcn_mfma_f32_16x16x32_bf16(b1p1[kc], am[kc][jt], hacc[jt], 0, 0, 0);
    } else {
      #pragma unroll
      for (int kc = 0; kc < 4; ++kc)
        #pragma unroll
        for (int jt = 0; jt < 4; ++jt)
          hacc[jt] = __builtin_amdgcn_mfma_f32_16x16x32_bf16(b1p0[kc], am[kc][jt], hacc[jt], 0, 0, 0);
    }
    // W2 slice for this nt
    short8 a2w[2][2];
    #pragma unroll
    for (int kc2 = 0; kc2 < 2; ++kc2)
      #pragma unroll
      for (int it = 0; it < 2; ++it)
        a2w[kc2][it] = *(const short8*)(w2T + (size_t)(wv * 32 + it * 16 + m) * 512 +
                                       nt * 64 + kc2 * 32 + q4 * 8);
    // GELU + bias -> H (b64 per jt)
    f32x4 b1v = *(const f32x4*)(bb1 + nt * 64 + wv * 16 + q4 * 4);
    #pragma unroll
    for (int jt = 0; jt < 4; ++jt) {
      float g[4];
      #pragma unroll
      for (int rr = 0; rr < 4; ++rr) {
        float v = hacc[jt][rr] + b1v[rr];
        float v2 = v * v;
        float qe = v * __builtin_fmaf(-0.07135482f, v2, -1.5957691f);
        float te = __expf(qe);
        g[rr] = v * __builtin_amdgcn_rcpf(1.f + te);
      }
      u32x2 w = {pk2(g[0], g[1]), pk2(g[2], g[3])};
      *(u32x2*)(Hb + (jt * 16 + m) * 144 + wv * 32 + q4 * 8) = w;
    }
    __syncthreads();   // H tile ready (double-buffered; one barrier/iter)

    // refill consumed W1 buffer (post-barrier; never drained early)
    if (nt < 6) {
      const u16* p = w1base + (size_t)(nt + 2) * 64 * 128;
      if (nt & 1) {
        #pragma unroll
        for (int kc = 0; kc < 4; ++kc) b1p1[kc] = *(const short8*)(p + kc * 32);
      } else {
        #pragma unroll
        for (int kc = 0; kc < 4; ++kc) b1p0[kc] = *(const short8*)(p + kc * 32);
      }
    }

    // GEMM2 (swapped): acc[col][tok] += W2-slice x H
    #pragma unroll
    for (int kc2 = 0; kc2 < 2; ++kc2) {
      short8 hf[4];
      #pragma unroll
      for (int jt = 0; jt < 4; ++jt)
        hf[jt] = *(const short8*)(Hb + (jt * 16 + m) * 144 + kc2 * 64 + q4 * 16);
      #pragma unroll
      for (int it = 0; it < 2; ++it)
        #pragma unroll
        for (int jt = 0; jt < 4; ++jt)
          acc[it][jt] = __builtin_amdgcn_mfma_f32_16x16x32_bf16(a2w[kc2][it], hf[jt], acc[it][jt], 0, 0, 0);
    }
  }

  // ---- epilogue: out[tok][col..col+3] = 0.5*(mlp+bb2) + xreg, dwordx4 stores ----
  f32x4 ob[2];
  #pragma unroll
  for (int it = 0; it < 2; ++it)
    ob[it] = *(const f32x4*)(bb2 + wv * 32 + it * 16 + q4 * 4);
  #pragma unroll
  for (int it = 0; it < 2; ++it)
    #pragma unroll
    for (int jt = 0; jt < 4; ++jt) {
      f32x4 v;
      #pragma unroll
      for (int rr = 0; rr < 4; ++rr)
        v[rr] = 0.5f * (acc[it][jt][rr] + ob[it][rr]) + xr[it][jt][rr];
      *(f32x4*)(out + (size_t)origjt[jt] * 128 + wv * 32 + it * 16 + q4 * 4) = v;
    }
}

extern "C" void kernel_launch(void* const* d_in, const int* in_sizes, int n_in,
                              void* d_out, int out_size, void* d_ws, size_t ws_size,
                              hipStream_t stream) {
  const float* inputs = (const float*)d_in[0];
  const float* qkv_w  = (const float*)d_in[1];
  const float* proj_w = (const float*)d_in[2];
  const float* proj_b = (const float*)d_in[3];
  const float* btab   = (const float*)d_in[4];
  const float* g1     = (const float*)d_in[5];
  const float* b1     = (const float*)d_in[6];
  const float* g2     = (const float*)d_in[7];
  const float* b2     = (const float*)d_in[8];
  const float* w1     = (const float*)d_in[9];
  const float* bb1    = (const float*)d_in[10];
  const float* w2     = (const float*)d_in[11];
  const float* bb2    = (const float*)d_in[12];
  float* out = (float*)d_out;

  char* ws = (char*)d_ws;
  u16* qkvT  = (u16*)(ws + 0);          // 384*128 bf16
  u16* projT = (u16*)(ws + 98304);      // 128*128
  u16* w1T   = (u16*)(ws + 131072);     // 512*128
  u16* w2T   = (u16*)(ws + 262144);     // 128*512
  u32* bfrag = (u32*)(ws + 393216);     // 16*256*2 u32 bias fragments

  k_wprep4<<<49, 256, 0, stream>>>(qkv_w, proj_w, w1, w2, btab, qkvT, projT, w1T, w2T, bfrag);
  k_all<<<4096, 256, 0, stream>>>(inputs, qkvT, projT, proj_b, bfrag, g1, b1,
                                  w1T, w2T, g2, b2, bb1, bb2, out);
}

// Round 7
// 469.267 us; speedup vs baseline: 1.0927x; 1.0927x over previous
//
#include <hip/hip_runtime.h>
#include <hip/hip_bf16.h>

typedef unsigned short u16;
typedef unsigned int u32;
typedef __attribute__((ext_vector_type(8))) short short8;
typedef __attribute__((ext_vector_type(2))) unsigned int u32x2;
typedef __attribute__((ext_vector_type(4))) float f32x4;

__device__ __forceinline__ u16 f2bf(float x) {
  __hip_bfloat16 h = __float2bfloat16(x);
  return *reinterpret_cast<u16*>(&h);
}
__device__ __forceinline__ u32 pk2(float a, float b) {
  return (u32)f2bf(a) | ((u32)f2bf(b) << 16);
}
__device__ __forceinline__ float bflo(u32 u) { return __uint_as_float(u << 16); }
__device__ __forceinline__ float bfhi(u32 u) { return __uint_as_float(u & 0xffff0000u); }

// ---------------- weight transposes (48 blocks) + bias fragment precompute (block 48) ----------------
__global__ __launch_bounds__(256) void k_wprep4(const float* __restrict__ qkv_w,
                                                const float* __restrict__ proj_w,
                                                const float* __restrict__ w1,
                                                const float* __restrict__ w2,
                                                const float* __restrict__ btab,
                                                u16* __restrict__ qkvT, u16* __restrict__ projT,
                                                u16* __restrict__ w1T, u16* __restrict__ w2T,
                                                u32* __restrict__ bfrag) {
  const int b = blockIdx.x, t = threadIdx.x;
  if (b == 48) {
    const int h = t >> 6, m = t & 15, q4 = (t >> 4) & 3;
    const int my = m >> 2, mz = m & 3;
    for (int g = 0; g < 16; ++g) {
      int ti = g >> 2, tj = g & 3;
      int base = 11 * (tj - ti + 3) + (my - q4 + 3) + (mz + 3);
      float v0 = btab[(base - 0) * 4 + h];
      float v1 = btab[(base - 1) * 4 + h];
      float v2 = btab[(base - 2) * 4 + h];
      float v3 = btab[(base - 3) * 4 + h];
      bfrag[(g * 256 + t) * 2 + 0] = pk2(v0, v1);
      bfrag[(g * 256 + t) * 2 + 1] = pk2(v2, v3);
    }
    return;
  }
  __shared__ float tile[64][65];
  const float* src; u16* dst; int K, N, tk, tn;
  if (b < 12)      { src = qkv_w;  dst = qkvT;  K = 128; N = 384; tk = b / 6;        tn = b % 6; }
  else if (b < 16) { src = proj_w; dst = projT; K = 128; N = 128; tk = (b - 12) / 2; tn = (b - 12) % 2; }
  else if (b < 32) { src = w1;     dst = w1T;   K = 128; N = 512; tk = (b - 16) / 8; tn = (b - 16) % 8; }
  else             { src = w2;     dst = w2T;   K = 512; N = 128; tk = (b - 32) / 2; tn = (b - 32) % 2; }
  const int rb = t >> 6, c = t & 63;
  #pragma unroll
  for (int i = 0; i < 16; ++i) {
    int r = i * 4 + rb;
    tile[r][c] = src[(size_t)(tk * 64 + r) * N + tn * 64 + c];
  }
  __syncthreads();
  #pragma unroll
  for (int i = 0; i < 16; ++i) {
    int rr = i * 4 + rb;
    dst[(size_t)(tn * 64 + rr) * K + tk * 64 + c] = f2bf(tile[c][rr]);
  }
}

// ---------------- R7: R6 structure with register-pressure fix (kill the xr spill) ----------------
// R6 post-mortem: VGPR=84 with ~165 live at the MLP peak => xr spilled to scratch =>
// +327MB HBM (FETCH 72->216, WRITE 131->314). R7 cuts the peak below the (256,3) cap of 170:
//   * am[4][4] NOT hoisted (-64 regs): A2 fragments read from LDS per-kc inside the nt loop.
//   * W1 prefetch 1-deep (-16 regs): b1p consumed at GEMM1, refilled post-barrier.
// Everything else identical to R6 (53248B LDS -> 3 blocks/CU, X-in-regs, swapped GEMMs).
__global__ __launch_bounds__(256, 3) void k_all(const float* __restrict__ inputs,
                                                const u16* __restrict__ qkvT,
                                                const u16* __restrict__ projT,
                                                const float* __restrict__ proj_b,
                                                const u32* __restrict__ bfrag,
                                                const float* __restrict__ g1,
                                                const float* __restrict__ b1,
                                                const u16* __restrict__ w1T,
                                                const u16* __restrict__ w2T,
                                                const float* __restrict__ g2,
                                                const float* __restrict__ b2,
                                                const float* __restrict__ bb1,
                                                const float* __restrict__ bb2,
                                                float* __restrict__ out) {
  __shared__ __align__(16) char lds[53248];

  const int t = threadIdx.x, wv = t >> 6, lane = t & 63;
  const int m = lane & 15, q4 = lane >> 4;
  const int bw = blockIdx.x;
  const int wbox = bw & 511, bsm = bw >> 9;
  const int gx = wbox >> 6, gy = (wbox >> 3) & 7, gz = wbox & 7;

  // ---- LN1 with roll/partition gather (row r1), seg-reduce via shfl ----
  {
    const int r1 = t >> 2, seg = t & 3;
    const int ix = r1 >> 4, iy = (r1 >> 2) & 3, iz = r1 & 3;
    const int X = (gx * 4 + ix + 2) & 31, Y = (gy * 4 + iy + 2) & 31, Z = (gz * 4 + iz + 2) & 31;
    const size_t orig = ((size_t)bsm << 15) + (size_t)(X * 1024 + Y * 32 + Z);
    const float4* x4 = (const float4*)(inputs + orig * 128 + seg * 32);
    float vals[32];
    float s = 0.f, ss = 0.f;
    #pragma unroll
    for (int i = 0; i < 8; ++i) {
      float4 v = x4[i];
      vals[4 * i] = v.x; vals[4 * i + 1] = v.y; vals[4 * i + 2] = v.z; vals[4 * i + 3] = v.w;
      s += v.x + v.y + v.z + v.w;
      ss += v.x * v.x + v.y * v.y + v.z * v.z + v.w * v.w;
    }
    s += __shfl_xor(s, 1, 64);  s += __shfl_xor(s, 2, 64);
    ss += __shfl_xor(ss, 1, 64); ss += __shfl_xor(ss, 2, 64);
    float mean = s * 0.0078125f;
    float var = ss * 0.0078125f - mean * mean;
    float rs = rsqrtf(var + 1e-5f);
    #pragma unroll
    for (int v8 = 0; v8 < 4; ++v8) {
      short8 w;
      #pragma unroll
      for (int j = 0; j < 8; ++j) {
        int c = seg * 32 + v8 * 8 + j;
        w[j] = (short)f2bf((vals[v8 * 8 + j] - mean) * rs * g1[c] + b1[c]);
      }
      *(short8*)(lds + r1 * 272 + seg * 64 + v8 * 16) = w;
    }
  }
  __syncthreads();   // (b1) A ready

  // ---- A fragments (all 64 rows) ----
  short8 af[4][4];   // [kc][jt]
  #pragma unroll
  for (int kc = 0; kc < 4; ++kc)
    #pragma unroll
    for (int jt = 0; jt < 4; ++jt)
      af[kc][jt] = *(const short8*)(lds + (jt * 16 + m) * 272 + kc * 64 + q4 * 16);
  __syncthreads();   // (b1.5) af reads done -> Q may overlay A

  f32x4 zero = {0.f, 0.f, 0.f, 0.f};

  // ---- Q GEMM (swapped) -> Q[tok][col] @0, scaled ----
  {
    short8 wq[4][2];
    #pragma unroll
    for (int kc = 0; kc < 4; ++kc)
      #pragma unroll
      for (int it = 0; it < 2; ++it)
        wq[kc][it] = *(const short8*)(qkvT + (size_t)(wv * 32 + it * 16 + m) * 128 + kc * 32 + q4 * 8);
    f32x4 acc[2][4];
    #pragma unroll
    for (int it = 0; it < 2; ++it)
      #pragma unroll
      for (int jt = 0; jt < 4; ++jt) acc[it][jt] = zero;
    #pragma unroll
    for (int kc = 0; kc < 4; ++kc)
      #pragma unroll
      for (int it = 0; it < 2; ++it)
        #pragma unroll
        for (int jt = 0; jt < 4; ++jt)
          acc[it][jt] = __builtin_amdgcn_mfma_f32_16x16x32_bf16(wq[kc][it], af[kc][jt], acc[it][jt], 0, 0, 0);
    #pragma unroll
    for (int it = 0; it < 2; ++it)
      #pragma unroll
      for (int jt = 0; jt < 4; ++jt) {
        f32x4 a = acc[it][jt];
        u32x2 w = {pk2(a[0] * 0.17677669529663687f, a[1] * 0.17677669529663687f),
                   pk2(a[2] * 0.17677669529663687f, a[3] * 0.17677669529663687f)};
        *(u32x2*)(lds + (jt * 16 + m) * 272 + (wv * 32 + it * 16 + q4 * 4) * 2) = w;
      }
  }

  // ---- K GEMM (swapped) -> K[tok][col] @17408 ----
  {
    short8 wk[4][2];
    #pragma unroll
    for (int kc = 0; kc < 4; ++kc)
      #pragma unroll
      for (int it = 0; it < 2; ++it)
        wk[kc][it] = *(const short8*)(qkvT + (size_t)(128 + wv * 32 + it * 16 + m) * 128 + kc * 32 + q4 * 8);
    f32x4 acc[2][4];
    #pragma unroll
    for (int it = 0; it < 2; ++it)
      #pragma unroll
      for (int jt = 0; jt < 4; ++jt) acc[it][jt] = zero;
    #pragma unroll
    for (int kc = 0; kc < 4; ++kc)
      #pragma unroll
      for (int it = 0; it < 2; ++it)
        #pragma unroll
        for (int jt = 0; jt < 4; ++jt)
          acc[it][jt] = __builtin_amdgcn_mfma_f32_16x16x32_bf16(wk[kc][it], af[kc][jt], acc[it][jt], 0, 0, 0);
    #pragma unroll
    for (int it = 0; it < 2; ++it)
      #pragma unroll
      for (int jt = 0; jt < 4; ++jt) {
        f32x4 a = acc[it][jt];
        u32x2 w = {pk2(a[0], a[1]), pk2(a[2], a[3])};
        *(u32x2*)(lds + 17408 + (jt * 16 + m) * 272 + (wv * 32 + it * 16 + q4 * 4) * 2) = w;
      }
  }

  // ---- V GEMM (original) -> Vt[d][tok] @34816 ----
  {
    short8 wvv[4][2];
    #pragma unroll
    for (int kc = 0; kc < 4; ++kc)
      #pragma unroll
      for (int n2 = 0; n2 < 2; ++n2)
        wvv[kc][n2] = *(const short8*)(qkvT + (size_t)(256 + wv * 32 + n2 * 16 + m) * 128 + kc * 32 + q4 * 8);
    f32x4 acc[4][2];
    #pragma unroll
    for (int mt = 0; mt < 4; ++mt)
      #pragma unroll
      for (int n2 = 0; n2 < 2; ++n2) acc[mt][n2] = zero;
    #pragma unroll
    for (int kc = 0; kc < 4; ++kc)
      #pragma unroll
      for (int mt = 0; mt < 4; ++mt)
        #pragma unroll
        for (int n2 = 0; n2 < 2; ++n2)
          acc[mt][n2] = __builtin_amdgcn_mfma_f32_16x16x32_bf16(af[kc][mt], wvv[kc][n2], acc[mt][n2], 0, 0, 0);
    #pragma unroll
    for (int mt = 0; mt < 4; ++mt)
      #pragma unroll
      for (int n2 = 0; n2 < 2; ++n2) {
        f32x4 a = acc[mt][n2];
        u32x2 w = {pk2(a[0], a[1]), pk2(a[2], a[3])};
        *(u32x2*)(lds + 34816 + wv * 4608 + (n2 * 16 + m) * 144 + mt * 32 + q4 * 8) = w;
      }
  }

  // ---- qf/kf fragments + bias fragments ----
  short8 qf[4], kf[4];
  #pragma unroll
  for (int ti = 0; ti < 4; ++ti) {
    qf[ti] = *(const short8*)(lds + (ti * 16 + m) * 272 + wv * 64 + q4 * 16);
    kf[ti] = *(const short8*)(lds + 17408 + (ti * 16 + m) * 272 + wv * 64 + q4 * 16);
  }
  u32x2 bu[16];
  #pragma unroll
  for (int g = 0; g < 16; ++g)
    bu[g] = *(const u32x2*)(bfrag + (g * 256 + t) * 2);
  __syncthreads();   // (b2) Q/K reads done -> P may overlay

  // ---- S^T = mfma(K,Q) ----
  f32x4 S[4][4];
  #pragma unroll
  for (int ti = 0; ti < 4; ++ti)
    #pragma unroll
    for (int tj = 0; tj < 4; ++tj) S[ti][tj] = zero;
  #pragma unroll
  for (int ti = 0; ti < 4; ++ti)
    #pragma unroll
    for (int tj = 0; tj < 4; ++tj)
      S[ti][tj] = __builtin_amdgcn_mfma_f32_16x16x32_bf16(kf[ti], qf[tj], S[ti][tj], 0, 0, 0);

  // ---- bias + mask ----
  int catx[4], caty[4], catz[4];
  #pragma unroll
  for (int a = 0; a < 4; ++a) {
    catx[a] = (gx < 7) ? 0 : ((a < 2) ? 1 : 2);
    caty[a] = (gy < 7) ? 0 : ((a < 2) ? 1 : 2);
    catz[a] = (gz < 7) ? 0 : ((a < 2) ? 1 : 2);
  }
  const int cy = (m >> 2) & 3, cz = m & 3;
  int labq[4], labk[16];
  #pragma unroll
  for (int tj = 0; tj < 4; ++tj) labq[tj] = catx[tj] * 9 + caty[cy] * 3 + catz[cz];
  #pragma unroll
  for (int ti = 0; ti < 4; ++ti)
    #pragma unroll
    for (int rr = 0; rr < 4; ++rr) labk[ti * 4 + rr] = catx[ti] * 9 + caty[q4] * 3 + catz[rr];

  #pragma unroll
  for (int ti = 0; ti < 4; ++ti)
    #pragma unroll
    for (int tj = 0; tj < 4; ++tj) {
      u32x2 bp = bu[ti * 4 + tj];
      #pragma unroll
      for (int rr = 0; rr < 4; ++rr) {
        float bv = (rr & 1) ? bfhi(bp[rr >> 1]) : bflo(bp[rr >> 1]);
        float v = S[ti][tj][rr] + bv;
        if (labk[ti * 4 + rr] != labq[tj]) v -= 100.f;
        S[ti][tj][rr] = v;
      }
    }

  // ---- softmax over k ----
  float mx[4], sm[4];
  #pragma unroll
  for (int tj = 0; tj < 4; ++tj) {
    float v = fmaxf(fmaxf(S[0][tj][0], S[0][tj][1]), fmaxf(S[0][tj][2], S[0][tj][3]));
    #pragma unroll
    for (int ti = 1; ti < 4; ++ti)
      v = fmaxf(v, fmaxf(fmaxf(S[ti][tj][0], S[ti][tj][1]), fmaxf(S[ti][tj][2], S[ti][tj][3])));
    v = fmaxf(v, __shfl_xor(v, 16, 64));
    v = fmaxf(v, __shfl_xor(v, 32, 64));
    mx[tj] = v;
  }
  #pragma unroll
  for (int tj = 0; tj < 4; ++tj) {
    float s = 0.f;
    #pragma unroll
    for (int ti = 0; ti < 4; ++ti)
      #pragma unroll
      for (int rr = 0; rr < 4; ++rr) {
        float e = __expf(S[ti][tj][rr] - mx[tj]);
        S[ti][tj][rr] = e;
        s += e;
      }
    s += __shfl_xor(s, 16, 64);
    s += __shfl_xor(s, 32, 64);
    sm[tj] = 1.f / s;
  }

  // ---- P[q][k] per-head @ wv*8704 ----
  #pragma unroll
  for (int ti = 0; ti < 4; ++ti)
    #pragma unroll
    for (int tj = 0; tj < 4; ++tj) {
      f32x4 a = S[ti][tj];
      u32x2 w = {pk2(a[0], a[1]), pk2(a[2], a[3])};
      *(u32x2*)(lds + wv * 8704 + (tj * 16 + m) * 136 + ti * 32 + q4 * 8) = w;
    }

  // ---- PV (swapped: D[d][q]) ----
  f32x4 accO[2][4];
  #pragma unroll
  for (int it = 0; it < 2; ++it)
    #pragma unroll
    for (int jt = 0; jt < 4; ++jt) accO[it][jt] = zero;
  #pragma unroll
  for (int ks = 0; ks < 2; ++ks) {
    short8 vb[2], pa[4];
    #pragma unroll
    for (int it = 0; it < 2; ++it)
      vb[it] = *(const short8*)(lds + 34816 + wv * 4608 + (it * 16 + m) * 144 + ks * 64 + q4 * 16);
    #pragma unroll
    for (int jt = 0; jt < 4; ++jt) {
      u32x2 lo = *(const u32x2*)(lds + wv * 8704 + (jt * 16 + m) * 136 + ks * 64 + q4 * 16);
      u32x2 hi = *(const u32x2*)(lds + wv * 8704 + (jt * 16 + m) * 136 + ks * 64 + q4 * 16 + 8);
      union { u32 u[4]; short8 s; } c;
      c.u[0] = lo[0]; c.u[1] = lo[1]; c.u[2] = hi[0]; c.u[3] = hi[1];
      pa[jt] = c.s;
    }
    #pragma unroll
    for (int it = 0; it < 2; ++it)
      #pragma unroll
      for (int jt = 0; jt < 4; ++jt)
        accO[it][jt] = __builtin_amdgcn_mfma_f32_16x16x32_bf16(vb[it], pa[jt], accO[it][jt], 0, 0, 0);
  }
  __syncthreads();   // (b3) PV done -> P,Vt dead -> O overlay

  // ---- O[tok][d] @0, normalized ----
  #pragma unroll
  for (int it = 0; it < 2; ++it)
    #pragma unroll
    for (int jt = 0; jt < 4; ++jt) {
      f32x4 a = accO[it][jt];
      float sc = sm[jt];
      u32x2 w = {pk2(a[0] * sc, a[1] * sc), pk2(a[2] * sc, a[3] * sc)};
      *(u32x2*)(lds + (jt * 16 + m) * 272 + (wv * 32 + it * 16 + q4 * 4) * 2) = w;
    }
  __syncthreads();   // (b4) O ready

  // ---- proj (swapped); residual into registers ----
  int origjt[4];
  #pragma unroll
  for (int jt = 0; jt < 4; ++jt) {
    int X = (gx * 4 + jt + 2) & 31, Y = (gy * 4 + (m >> 2) + 2) & 31, Z = (gz * 4 + (m & 3) + 2) & 31;
    origjt[jt] = (bsm << 15) + X * 1024 + Y * 32 + Z;
  }
  f32x4 xr[2][4];
  {
    short8 bp[4][2], of[4][4];
    #pragma unroll
    for (int kc = 0; kc < 4; ++kc)
      #pragma unroll
      for (int it = 0; it < 2; ++it)
        bp[kc][it] = *(const short8*)(projT + (size_t)(wv * 32 + it * 16 + m) * 128 + kc * 32 + q4 * 8);
    f32x4 inr[2][4];
    #pragma unroll
    for (int it = 0; it < 2; ++it)
      #pragma unroll
      for (int jt = 0; jt < 4; ++jt)
        inr[it][jt] = *(const f32x4*)(inputs + (size_t)origjt[jt] * 128 + wv * 32 + it * 16 + q4 * 4);
    f32x4 pbv[2];
    #pragma unroll
    for (int it = 0; it < 2; ++it)
      pbv[it] = *(const f32x4*)(proj_b + wv * 32 + it * 16 + q4 * 4);
    #pragma unroll
    for (int kc = 0; kc < 4; ++kc)
      #pragma unroll
      for (int jt = 0; jt < 4; ++jt)
        of[kc][jt] = *(const short8*)(lds + (jt * 16 + m) * 272 + kc * 64 + q4 * 16);
    f32x4 acc[2][4];
    #pragma unroll
    for (int it = 0; it < 2; ++it)
      #pragma unroll
      for (int jt = 0; jt < 4; ++jt) acc[it][jt] = zero;
    #pragma unroll
    for (int kc = 0; kc < 4; ++kc)
      #pragma unroll
      for (int it = 0; it < 2; ++it)
        #pragma unroll
        for (int jt = 0; jt < 4; ++jt)
          acc[it][jt] = __builtin_amdgcn_mfma_f32_16x16x32_bf16(bp[kc][it], of[kc][jt], acc[it][jt], 0, 0, 0);
    #pragma unroll
    for (int it = 0; it < 2; ++it)
      #pragma unroll
      for (int jt = 0; jt < 4; ++jt)
        #pragma unroll
        for (int rr = 0; rr < 4; ++rr)
          xr[it][jt][rr] = 0.5f * (acc[it][jt][rr] + pbv[it][rr]) + inr[it][jt][rr];
  }
  __syncthreads();   // (b4.5) O reads done -> A2/red writable

  // ---- LN2 stats (cross-wave via red @34816) ----
  float* red = (float*)(lds + 34816);
  {
    float sp[4], ssp[4];
    #pragma unroll
    for (int jt = 0; jt < 4; ++jt) {
      float s = 0.f, ss2 = 0.f;
      #pragma unroll
      for (int it = 0; it < 2; ++it)
        #pragma unroll
        for (int rr = 0; rr < 4; ++rr) {
          float v = xr[it][jt][rr];
          s += v; ss2 += v * v;
        }
      s += __shfl_xor(s, 16, 64);  s += __shfl_xor(s, 32, 64);
      ss2 += __shfl_xor(ss2, 16, 64); ss2 += __shfl_xor(ss2, 32, 64);
      sp[jt] = s; ssp[jt] = ss2;
    }
    if (q4 == 0) {
      #pragma unroll
      for (int jt = 0; jt < 4; ++jt) {
        red[(jt * 16 + m) * 8 + wv * 2 + 0] = sp[jt];
        red[(jt * 16 + m) * 8 + wv * 2 + 1] = ssp[jt];
      }
    }
  }
  __syncthreads();   // (b4.75) red ready

  // ---- normalize -> A2[tok][col] @17408 ----
  {
    f32x4 g2v[2], b2v[2];
    #pragma unroll
    for (int it = 0; it < 2; ++it) {
      g2v[it] = *(const f32x4*)(g2 + wv * 32 + it * 16 + q4 * 4);
      b2v[it] = *(const f32x4*)(b2 + wv * 32 + it * 16 + q4 * 4);
    }
    #pragma unroll
    for (int jt = 0; jt < 4; ++jt) {
      f32x4 r0 = *(const f32x4*)(red + (jt * 16 + m) * 8);
      f32x4 r1 = *(const f32x4*)(red + (jt * 16 + m) * 8 + 4);
      float sum = r0[0] + r0[2] + r1[0] + r1[2];
      float sq  = r0[1] + r0[3] + r1[1] + r1[3];
      float mean = sum * 0.0078125f;
      float var = sq * 0.0078125f - mean * mean;
      float rs = rsqrtf(var + 1e-5f);
      #pragma unroll
      for (int it = 0; it < 2; ++it) {
        float n0 = (xr[it][jt][0] - mean) * rs * g2v[it][0] + b2v[it][0];
        float n1 = (xr[it][jt][1] - mean) * rs * g2v[it][1] + b2v[it][1];
        float n2 = (xr[it][jt][2] - mean) * rs * g2v[it][2] + b2v[it][2];
        float n3 = (xr[it][jt][3] - mean) * rs * g2v[it][3] + b2v[it][3];
        u32x2 w = {pk2(n0, n1), pk2(n2, n3)};
        *(u32x2*)(lds + 17408 + (jt * 16 + m) * 272 + (wv * 32 + it * 16 + q4 * 4) * 2) = w;
      }
    }
  }
  __syncthreads();   // (b5) A2 ready; red dead -> H0 writable

  // ---- MLP: A2 frags read per-iteration from LDS (NOT hoisted; spill fix) ----
  const u16* w1base = w1T + (size_t)(wv * 16 + m) * 128 + q4 * 8;
  short8 b1p[4];
  #pragma unroll
  for (int kc = 0; kc < 4; ++kc) b1p[kc] = *(const short8*)(w1base + kc * 32);

  f32x4 acc[2][4];
  #pragma unroll
  for (int it = 0; it < 2; ++it)
    #pragma unroll
    for (int jt = 0; jt < 4; ++jt) acc[it][jt] = zero;

  #pragma unroll
  for (int nt = 0; nt < 8; ++nt) {
    char* Hb = lds + 34816 + (nt & 1) * 9216;
    // GEMM1 (swapped): D[hcol][tok]; A2 fragments from LDS per kc
    f32x4 hacc[4];
    #pragma unroll
    for (int jt = 0; jt < 4; ++jt) hacc[jt] = zero;
    #pragma unroll
    for (int kc = 0; kc < 4; ++kc) {
      short8 amk[4];
      #pragma unroll
      for (int jt = 0; jt < 4; ++jt)
        amk[jt] = *(const short8*)(lds + 17408 + (jt * 16 + m) * 272 + kc * 64 + q4 * 16);
      #pragma unroll
      for (int jt = 0; jt < 4; ++jt)
        hacc[jt] = __builtin_amdgcn_mfma_f32_16x16x32_bf16(b1p[kc], amk[jt], hacc[jt], 0, 0, 0);
    }
    // W2 slice for this nt
    short8 a2w[2][2];
    #pragma unroll
    for (int kc2 = 0; kc2 < 2; ++kc2)
      #pragma unroll
      for (int it = 0; it < 2; ++it)
        a2w[kc2][it] = *(const short8*)(w2T + (size_t)(wv * 32 + it * 16 + m) * 512 +
                                       nt * 64 + kc2 * 32 + q4 * 8);
    // GELU + bias -> H
    f32x4 b1v = *(const f32x4*)(bb1 + nt * 64 + wv * 16 + q4 * 4);
    #pragma unroll
    for (int jt = 0; jt < 4; ++jt) {
      float g[4];
      #pragma unroll
      for (int rr = 0; rr < 4; ++rr) {
        float v = hacc[jt][rr] + b1v[rr];
        float v2 = v * v;
        float qe = v * __builtin_fmaf(-0.07135482f, v2, -1.5957691f);
        float te = __expf(qe);
        g[rr] = v * __builtin_amdgcn_rcpf(1.f + te);
      }
      u32x2 w = {pk2(g[0], g[1]), pk2(g[2], g[3])};
      *(u32x2*)(Hb + (jt * 16 + m) * 144 + wv * 32 + q4 * 8) = w;
    }
    __syncthreads();   // H tile ready

    // refill W1 for nt+1 (post-barrier; latency hidden under GEMM2)
    if (nt < 7) {
      const u16* p = w1base + (size_t)(nt + 1) * 64 * 128;
      #pragma unroll
      for (int kc = 0; kc < 4; ++kc) b1p[kc] = *(const short8*)(p + kc * 32);
    }

    // GEMM2 (swapped): acc[col][tok] += W2-slice x H
    #pragma unroll
    for (int kc2 = 0; kc2 < 2; ++kc2) {
      short8 hf[4];
      #pragma unroll
      for (int jt = 0; jt < 4; ++jt)
        hf[jt] = *(const short8*)(Hb + (jt * 16 + m) * 144 + kc2 * 64 + q4 * 16);
      #pragma unroll
      for (int it = 0; it < 2; ++it)
        #pragma unroll
        for (int jt = 0; jt < 4; ++jt)
          acc[it][jt] = __builtin_amdgcn_mfma_f32_16x16x32_bf16(a2w[kc2][it], hf[jt], acc[it][jt], 0, 0, 0);
    }
  }

  // ---- epilogue: out = 0.5*(mlp+bb2) + xr, dwordx4 stores ----
  f32x4 ob[2];
  #pragma unroll
  for (int it = 0; it < 2; ++it)
    ob[it] = *(const f32x4*)(bb2 + wv * 32 + it * 16 + q4 * 4);
  #pragma unroll
  for (int it = 0; it < 2; ++it)
    #pragma unroll
    for (int jt = 0; jt < 4; ++jt) {
      f32x4 v;
      #pragma unroll
      for (int rr = 0; rr < 4; ++rr)
        v[rr] = 0.5f * (acc[it][jt][rr] + ob[it][rr]) + xr[it][jt][rr];
      *(f32x4*)(out + (size_t)origjt[jt] * 128 + wv * 32 + it * 16 + q4 * 4) = v;
    }
}

extern "C" void kernel_launch(void* const* d_in, const int* in_sizes, int n_in,
                              void* d_out, int out_size, void* d_ws, size_t ws_size,
                              hipStream_t stream) {
  const float* inputs = (const float*)d_in[0];
  const float* qkv_w  = (const float*)d_in[1];
  const float* proj_w = (const float*)d_in[2];
  const float* proj_b = (const float*)d_in[3];
  const float* btab   = (const float*)d_in[4];
  const float* g1     = (const float*)d_in[5];
  const float* b1     = (const float*)d_in[6];
  const float* g2     = (const float*)d_in[7];
  const float* b2     = (const float*)d_in[8];
  const float* w1     = (const float*)d_in[9];
  const float* bb1    = (const float*)d_in[10];
  const float* w2     = (const float*)d_in[11];
  const float* bb2    = (const float*)d_in[12];
  float* out = (float*)d_out;

  char* ws = (char*)d_ws;
  u16* qkvT  = (u16*)(ws + 0);          // 384*128 bf16
  u16* projT = (u16*)(ws + 98304);      // 128*128
  u16* w1T   = (u16*)(ws + 131072);     // 512*128
  u16* w2T   = (u16*)(ws + 262144);     // 128*512
  u32* bfrag = (u32*)(ws + 393216);     // 16*256*2 u32 bias fragments

  k_wprep4<<<49, 256, 0, stream>>>(qkv_w, proj_w, w1, w2, btab, qkvT, projT, w1T, w2T, bfrag);
  k_all<<<4096, 256, 0, stream>>>(inputs, qkvT, projT, proj_b, bfrag, g1, b1,
                                  w1T, w2T, g2, b2, bb1, bb2, out);
}